// Round 12
// baseline (124.210 us; speedup 1.0000x reference)
//
#include <hip/hip_runtime.h>
#include <math.h>

#define B 8
#define T 512
#define D 1024
#define H 16
#define DH 64

typedef __bf16 bf16;
typedef __attribute__((ext_vector_type(8))) __bf16 bf16x8;
typedef __attribute__((ext_vector_type(4))) __bf16 bf16x4;
typedef __attribute__((ext_vector_type(4))) float f32x4;

// Async global->LDS, 16 B per lane. LDS dest = wave-uniform base + lane*16.
__device__ __forceinline__ void gld16(const void* g, void* l) {
    __builtin_amdgcn_global_load_lds(
        (const __attribute__((address_space(1))) void*)g,
        (__attribute__((address_space(3))) void*)l, 16, 0, 0);
}

// MFMA 16x16x32 bf16 layouts (HW-verified per guide m89/m120):
//   A[m][k]: m = lane&15, k = (lane>>4)*8 + j
//   B[k][n]: n = lane&15, k = (lane>>4)*8 + j   (same lane map as A!)
//   C/D    : col = lane&15, row = (lane>>4)*4 + reg
// mfma(x,y) with both frags read at rows base+l15 yields
// D[x-row = quad*4+reg][y-row = l15].
//
// R12 (vs R11-best 121.9us), three independent low-risk levers:
//  (1) riders FIRST (bid<256): grid 768 @ 2 blocks/CU = 1.5 rounds; with
//      riders last they serialize as a tail round after attn. Riders first
//      -> they vacate in ~2-3us and attn backfills (ascending-dispatch
//      hypothesis; neutral if wrong).
//  (2) fuse: T5 s_setprio around the MFMA cluster (counted-vmcnt pipeline
//      gives wave role-diversity -> setprio has something to arbitrate).
//  (3) attn: mask via direct per-lane int4 global prefetch (L2-hot 8KB),
//      issued with the X prefetch, in flight across the T4 barrier ->
//      msk LDS write+read+barrier-coupling deleted.
// Arithmetic stream unchanged -> absmax expected EXACTLY 0.004882812.

#define EXP2SCALE 1.44269504088896f   // log2(e); folded into Q pre-scale

// ---------------------------------------------------------------------------
// Kernel A: bid<256  -> Wf -> WfT [n][k] bf16 transpose tile (rider, FIRST).
//           bid>=256 -> fused qkv + flash attention (R11 K-elim structure).
// ---------------------------------------------------------------------------
__global__ __launch_bounds__(256, 2) void qkv_attn(
    const float* __restrict__ X, const int* __restrict__ mask,
    const float* __restrict__ Wq, const float* __restrict__ Wk,
    const float* __restrict__ Wv,
    const float* __restrict__ bq, const float* __restrict__ bv,
    const float* __restrict__ Wf, bf16* __restrict__ WfT,
    bf16* __restrict__ Ob)
{
    __shared__ __align__(16) char smem[61440];

    if (blockIdx.x < 256) {
        // ---- Wf transpose rider blocks (verified body; now scheduled first)
        bf16* Ts = (bf16*)smem;   // 64 x 72
        const int ti = blockIdx.x, tid = threadIdx.x;
        const int k0 = (ti >> 4) * 64, n0 = (ti & 15) * 64;
        for (int i = tid; i < 1024; i += 256) {
            const int k = i >> 4, nq = (i & 15) * 4;
            const float4 w = *(const float4*)(Wf + (size_t)(k0 + k) * D + n0 + nq);
            Ts[(nq + 0) * 72 + k] = (bf16)w.x; Ts[(nq + 1) * 72 + k] = (bf16)w.y;
            Ts[(nq + 2) * 72 + k] = (bf16)w.z; Ts[(nq + 3) * 72 + k] = (bf16)w.w;
        }
        __syncthreads();
        for (int i = tid; i < 512; i += 256) {
            const int n = i >> 3, kc = (i & 7) * 8;
            *(bf16x8*)(WfT + (size_t)(n0 + n) * D + k0 + kc) = *(const bf16x8*)&Ts[n * 72 + kc];
        }
        return;
    }

    // LDS map (61440 B):
    //   0     : Wvs [e][d] swz, 8192, persistent
    //   8192  : Xkt dbuf, 2 x 8192 ([key64][64] swz)
    //   24576 : Vts dbuf, 2 x 9216 ([e][key] p72)
    //   43008 : Pl, 4 wave strips 32x72 (18432)
    // setup aliases (dead regions; barriers enforce):
    //   Wqs  [e][d] = Xkt buf0 (8192)
    //   WksT [d][e] = Vts buf0 (8192 <= 9216)
    //   Xq / Stage / Ostage = Pl
    bf16* Wvs  = (bf16*)(smem);
    bf16* Pl   = (bf16*)(smem + 43008);
    bf16* Wqs  = (bf16*)(smem + 8192);
    bf16* WksT = (bf16*)(smem + 24576);
    bf16* Xq   = Pl;
    bf16* Stage = Pl;
    bf16* Ostage = Pl;

    const int abid = blockIdx.x - 256;
    const int bh = abid & 127, q0 = (abid >> 7) * 128;
    const int b = bh >> 4, h = bh & 15;
    const int tid = threadIdx.x, wave = tid >> 6, lane = tid & 63;
    const int quad = lane >> 4, l15 = lane & 15;

    // X key-tile prefetch addressing (wave w -> keys w*16..w*16+15)
    const int pkrow = wave * 16 + (lane >> 2);
    const int pc0 = (lane & 3) * 2;

    float bqr[4], bvr[4];
#pragma unroll
    for (int nt = 0; nt < 4; ++nt) {
        bqr[nt] = bq[h * DH + nt * 16 + l15];
        bvr[nt] = bv[h * DH + nt * 16 + l15];
    }

    // ---- prefetch tile 0 (X rows + mask int4s) into registers ----
    float4 px0, px1, px2, px3;
    {
        const float* src = X + (size_t)(b * T + pkrow) * D + h * DH + pc0 * 8;
        px0 = *(const float4*)src; px1 = *(const float4*)(src + 4);
        px2 = *(const float4*)(src + 8); px3 = *(const float4*)(src + 12);
    }
    int4 mvc[4], mvn[4];
#pragma unroll
    for (int nt = 0; nt < 4; ++nt)
        mvc[nt] = *(const int4*)&mask[(size_t)b * T + nt * 16 + quad * 4];

    // ---- setup: W staging. Wq/Wv -> [e][d] swz (scalar); Wk -> [d][e] swz
    // (packed bf16x4: 4 consecutive e within one chunk). ----
    for (int i = tid; i < 1024; i += 256) {
        const int d = i >> 4, eq4 = (i & 15) * 4;
        const float4 wq4 = *(const float4*)(Wq + (size_t)h * 4096 + d * 64 + eq4);
        const float4 wk4 = *(const float4*)(Wk + (size_t)h * 4096 + d * 64 + eq4);
        const float4 wv4 = *(const float4*)(Wv + (size_t)h * 4096 + d * 64 + eq4);
#pragma unroll
        for (int j = 0; j < 4; ++j) {
            const int e = eq4 + j;
            const int idx = e * 64 + (((d >> 3) ^ (e & 7)) * 8) + (d & 7);
            Wqs[idx] = (bf16)((const float*)&wq4)[j];
            Wvs[idx] = (bf16)((const float*)&wv4)[j];
        }
        bf16x4 wkp;
        wkp[0] = (bf16)wk4.x; wkp[1] = (bf16)wk4.y;
        wkp[2] = (bf16)wk4.z; wkp[3] = (bf16)wk4.w;
        *(bf16x4*)&WksT[d * 64 + (((eq4 >> 3) ^ (d & 7)) * 8) + (eq4 & 7)] = wkp;
    }
    for (int i = tid; i < 1024; i += 256) {
        const int row = i >> 3, c = i & 7;
        const float* src = X + (size_t)(b * T + q0 + row) * D + h * DH + c * 8;
        const float4 x0 = *(const float4*)src;
        const float4 x1 = *(const float4*)(src + 4);
        bf16x8 t;
        t[0] = (bf16)x0.x; t[1] = (bf16)x0.y; t[2] = (bf16)x0.z; t[3] = (bf16)x0.w;
        t[4] = (bf16)x1.x; t[5] = (bf16)x1.y; t[6] = (bf16)x1.z; t[7] = (bf16)x1.w;
        *(bf16x8*)&Xq[row * 64 + ((c ^ (row & 7)) * 8)] = t;
    }
    __syncthreads();

    // ---- Q = Xq @ WqT (+bias, x 0.125*log2e), C-layout -> Stage -> qf ----
    {
        f32x4 accQ[2][4] = {};
#pragma unroll
        for (int ks = 0; ks < 2; ++ks) {
            bf16x8 af[2], bfr[4];
#pragma unroll
            for (int mt = 0; mt < 2; ++mt) {
                const int row = wave * 32 + mt * 16 + l15;
                af[mt] = *(const bf16x8*)&Xq[row * 64 + (((ks * 4 + quad) ^ (l15 & 7)) * 8)];
            }
#pragma unroll
            for (int nt = 0; nt < 4; ++nt)
                bfr[nt] = *(const bf16x8*)&Wqs[(nt * 16 + l15) * 64 + (((ks * 4 + quad) ^ (l15 & 7)) * 8)];
#pragma unroll
            for (int mt = 0; mt < 2; ++mt)
#pragma unroll
                for (int nt = 0; nt < 4; ++nt)
                    accQ[mt][nt] = __builtin_amdgcn_mfma_f32_16x16x32_bf16(af[mt], bfr[nt], accQ[mt][nt], 0, 0, 0);
        }
        __syncthreads();   // Xq/Wqs reads done everywhere (Wqs = Xkt buf0 freed)
        const float qs = 0.125f * EXP2SCALE;
#pragma unroll
        for (int mt = 0; mt < 2; ++mt)
#pragma unroll
            for (int nt = 0; nt < 4; ++nt)
#pragma unroll
                for (int reg = 0; reg < 4; ++reg)
                    Stage[(wave * 32 + mt * 16 + quad * 4 + reg) * 72 + nt * 16 + l15] =
                        (bf16)((accQ[mt][nt][reg] + bqr[nt]) * qs);
        __builtin_amdgcn_wave_barrier();
    }
    bf16x8 qf[2][2];
#pragma unroll
    for (int mt = 0; mt < 2; ++mt)
#pragma unroll
        for (int ks = 0; ks < 2; ++ks)
            qf[mt][ks] = *(const bf16x8*)&Stage[(wave * 32 + mt * 16 + l15) * 72 + ks * 32 + quad * 8];

    // ---- Qm = Qs @ Wk (K never materialized; see R11 derivation) ----
    bf16x8 qmf[2][2];
    {
        f32x4 accM[2][4] = {};
#pragma unroll
        for (int ks = 0; ks < 2; ++ks)
#pragma unroll
            for (int nt = 0; nt < 4; ++nt) {
                const bf16x8 wk8 = *(const bf16x8*)&WksT[(nt * 16 + l15) * 64 + (((ks * 4 + quad) ^ (l15 & 7)) * 8)];
#pragma unroll
                for (int mt = 0; mt < 2; ++mt)
                    accM[mt][nt] = __builtin_amdgcn_mfma_f32_16x16x32_bf16(wk8, qf[mt][ks], accM[mt][nt], 0, 0, 0);
            }
        __builtin_amdgcn_wave_barrier();   // qf reads complete (forced by mfma deps)
#pragma unroll
        for (int mt = 0; mt < 2; ++mt)
#pragma unroll
            for (int nt = 0; nt < 4; ++nt) {
                bf16x4 qp;
#pragma unroll
                for (int reg = 0; reg < 4; ++reg) qp[reg] = (bf16)accM[mt][nt][reg];
                *(bf16x4*)&Stage[(wave * 32 + mt * 16 + l15) * 72 + nt * 16 + quad * 4] = qp;
            }
        __builtin_amdgcn_wave_barrier();
#pragma unroll
        for (int mt = 0; mt < 2; ++mt)
#pragma unroll
            for (int ks = 0; ks < 2; ++ks)
                qmf[mt][ks] = *(const bf16x8*)&Stage[(wave * 32 + mt * 16 + l15) * 72 + ks * 32 + quad * 8];
    }
    __syncthreads();   // WksT (= Vts buf0) reads done everywhere before K-loop

    f32x4 acc[2][4] = {};
    float lst2[2] = {0.f, 0.f};

    // ---- K-loop: 8 tiles of 64 keys, ONE T4 barrier per tile ----
    for (int kt = 0; kt < 8; ++kt) {
        const int p = kt & 1;
        bf16* Xkt = (bf16*)(smem + 8192 + p * 8192);
        bf16* Vts = (bf16*)(smem + 24576 + p * 9216);

        // stage prefetched X -> Xkt[p] (own rows)
        {
            bf16x8 t0, t1;
            t0[0] = (bf16)px0.x; t0[1] = (bf16)px0.y; t0[2] = (bf16)px0.z; t0[3] = (bf16)px0.w;
            t0[4] = (bf16)px1.x; t0[5] = (bf16)px1.y; t0[6] = (bf16)px1.z; t0[7] = (bf16)px1.w;
            t1[0] = (bf16)px2.x; t1[1] = (bf16)px2.y; t1[2] = (bf16)px2.z; t1[3] = (bf16)px2.w;
            t1[4] = (bf16)px3.x; t1[5] = (bf16)px3.y; t1[6] = (bf16)px3.z; t1[7] = (bf16)px3.w;
            *(bf16x8*)&Xkt[pkrow * 64 + ((pc0 ^ (pkrow & 7)) * 8)] = t0;
            *(bf16x8*)&Xkt[pkrow * 64 + (((pc0 + 1) ^ (pkrow & 7)) * 8)] = t1;
        }
        __builtin_amdgcn_wave_barrier();   // wave-local Xkt write->read (afkv)

        // issue prefetch for tile kt+1 (X + mask; stays in flight across T4)
        if (kt < 7) {
            const float* src = X + (size_t)(b * T + (kt + 1) * 64 + pkrow) * D + h * DH + pc0 * 8;
            px0 = *(const float4*)src; px1 = *(const float4*)(src + 4);
            px2 = *(const float4*)(src + 8); px3 = *(const float4*)(src + 12);
#pragma unroll
            for (int nt = 0; nt < 4; ++nt)
                mvn[nt] = *(const int4*)&mask[(size_t)b * T + (kt + 1) * 64 + nt * 16 + quad * 4];
        }

        // V tile via MFMA (wave computes its own 16 keys); K path GONE.
        {
            bf16x8 afkv[2];
#pragma unroll
            for (int ks = 0; ks < 2; ++ks)
                afkv[ks] = *(const bf16x8*)&Xkt[(wave * 16 + l15) * 64 + (((ks * 4 + quad) ^ (l15 & 7)) * 8)];
            f32x4 accV[4] = {};
            __builtin_amdgcn_s_setprio(1);
#pragma unroll
            for (int ks = 0; ks < 2; ++ks)
#pragma unroll
                for (int nt = 0; nt < 4; ++nt) {
                    const bf16x8 bv8 = *(const bf16x8*)&Wvs[(nt * 16 + l15) * 64 + (((ks * 4 + quad) ^ (l15 & 7)) * 8)];
                    accV[nt] = __builtin_amdgcn_mfma_f32_16x16x32_bf16(afkv[ks], bv8, accV[nt], 0, 0, 0);
                }
            __builtin_amdgcn_s_setprio(0);
#pragma unroll
            for (int nt = 0; nt < 4; ++nt) {
                bf16x4 vp;
#pragma unroll
                for (int reg = 0; reg < 4; ++reg) vp[reg] = (bf16)accV[nt][reg];
                *(bf16x4*)&Vts[(nt * 16 + l15) * 72 + wave * 16 + quad * 4] = vp;
            }
        }
        // T4 barrier: LDS visibility only (Xkt all-rows + Vts);
        // thread-private VMEM prefetch stays in flight.
        asm volatile("s_waitcnt lgkmcnt(0)" ::: "memory");
        __builtin_amdgcn_s_barrier();

        // S^T = Xkt Qm^T directly: s[nt] holds S[key=nt*16+quad*4+reg][q=mt*16+l15]
        bf16* Plw = Pl + wave * (32 * 72);
        {
            bf16x8 xkf[4][2];
#pragma unroll
            for (int nt = 0; nt < 4; ++nt)
#pragma unroll
                for (int ks = 0; ks < 2; ++ks)
                    xkf[nt][ks] = *(const bf16x8*)&Xkt[(nt * 16 + l15) * 64 + (((ks * 4 + quad) ^ (l15 & 7)) * 8)];
#pragma unroll
            for (int mt = 0; mt < 2; ++mt) {
                f32x4 s[4] = {};
                __builtin_amdgcn_s_setprio(1);
#pragma unroll
                for (int ks = 0; ks < 2; ++ks)
#pragma unroll
                    for (int nt = 0; nt < 4; ++nt)
                        s[nt] = __builtin_amdgcn_mfma_f32_16x16x32_bf16(xkf[nt][ks], qmf[mt][ks], s[nt], 0, 0, 0);
                __builtin_amdgcn_s_setprio(0);
#pragma unroll
                for (int nt = 0; nt < 4; ++nt) {
                    bf16x4 pp;
                    const float p0 = (mvc[nt].x > 0) ? exp2f(s[nt][0]) : 0.f;
                    const float p1 = (mvc[nt].y > 0) ? exp2f(s[nt][1]) : 0.f;
                    const float p2 = (mvc[nt].z > 0) ? exp2f(s[nt][2]) : 0.f;
                    const float p3 = (mvc[nt].w > 0) ? exp2f(s[nt][3]) : 0.f;
                    lst2[mt] += (p0 + p1) + (p2 + p3);
                    pp[0] = (bf16)p0; pp[1] = (bf16)p1; pp[2] = (bf16)p2; pp[3] = (bf16)p3;
                    *(bf16x4*)&Plw[(mt * 16 + l15) * 72 + nt * 16 + quad * 4] = pp;
                }
            }
        }
        __builtin_amdgcn_wave_barrier();   // wave-local P write->read

        // O += P V
        __builtin_amdgcn_s_setprio(1);
#pragma unroll
        for (int kc = 0; kc < 2; ++kc) {
            const bf16x8 pf0 = *(const bf16x8*)&Plw[(l15) * 72 + kc * 32 + quad * 8];
            const bf16x8 pf1 = *(const bf16x8*)&Plw[(16 + l15) * 72 + kc * 32 + quad * 8];
#pragma unroll
            for (int nt = 0; nt < 4; ++nt) {
                const bf16x8 vf = *(const bf16x8*)&Vts[(nt * 16 + l15) * 72 + kc * 32 + quad * 8];
                acc[0][nt] = __builtin_amdgcn_mfma_f32_16x16x32_bf16(pf0, vf, acc[0][nt], 0, 0, 0);
                acc[1][nt] = __builtin_amdgcn_mfma_f32_16x16x32_bf16(pf1, vf, acc[1][nt], 0, 0, 0);
            }
        }
        __builtin_amdgcn_s_setprio(0);
#pragma unroll
        for (int nt = 0; nt < 4; ++nt) mvc[nt] = mvn[nt];
    }

    // ---- epilogue: reduce l across quads, redistribute, +bv, store ----
    __builtin_amdgcn_wave_barrier();
    float inv_r[2][4];
#pragma unroll
    for (int mt = 0; mt < 2; ++mt) {
        float l = lst2[mt];
        l += __shfl_xor(l, 16);
        l += __shfl_xor(l, 32);
        const float inv = 1.f / l;
#pragma unroll
        for (int reg = 0; reg < 4; ++reg)
            inv_r[mt][reg] = __shfl(inv, (lane & 48) | (quad * 4 + reg));
    }
#pragma unroll
    for (int mt = 0; mt < 2; ++mt)
#pragma unroll
        for (int reg = 0; reg < 4; ++reg) {
            const int row = wave * 32 + mt * 16 + quad * 4 + reg;   // own strip
#pragma unroll
            for (int nt = 0; nt < 4; ++nt)
                Ostage[row * 72 + nt * 16 + l15] =
                    (bf16)(acc[mt][nt][reg] * inv_r[mt][reg] + bvr[nt]);
        }
    __syncthreads();
    for (int i = tid; i < 1024; i += 256) {
        const int row = i >> 3, c = (i & 7) * 8;
        *(bf16x8*)(Ob + ((size_t)b * T + q0 + row) * D + h * DH + c) =
            *(const bf16x8*)&Ostage[row * 72 + c];
    }
}

// ---------------------------------------------------------------------------
// Kernel B: fusion GEMM, 128M x 64N, 512 thr (8 waves), grid (16,32)=512
// -> 2 blocks/CU = 4 waves/SIMD. TRIPLE-buffered, counted vmcnt pipeline
// (R9-verified) + R12: T5 setprio around the MFMA cluster.
// ---------------------------------------------------------------------------
__global__ __launch_bounds__(512, 4) void fuse_mfma(
    const bf16* __restrict__ Ob, const bf16* __restrict__ WfT,
    const float* __restrict__ bfv, float* __restrict__ out)
{
    __shared__ __align__(16) char smem[73728];
    // buf t%3 at t*24576: As 128x64 (16384 B) + Bs 64x64 (8192 B).

    const int col0 = blockIdx.x * 64;
    const int row0 = blockIdx.y * 128;
    const int tid = threadIdx.x, wave = tid >> 6, lane = tid & 63;
    const int quad = lane >> 4, l15 = lane & 15;
    const int lr = lane >> 3, lc = lane & 7;
    const int wm = (wave >> 1) * 32, wn = (wave & 1) * 32;

    f32x4 acc[2][2] = {};

    // per wave: 3 gld16 per stage (2 A-rows-of-8 + 1 B-rows-of-8)
    auto stage = [&](int t) {
        const int buf = t - (t / 3) * 3;
        bf16* As = (bf16*)(smem + buf * 24576);
        bf16* Bs = (bf16*)(smem + buf * 24576 + 16384);
        const int k0 = t * 64;
#pragma unroll
        for (int j = 0; j < 2; ++j) {
            const int row = wave * 16 + j * 8 + lr;
            gld16(Ob + (size_t)(row0 + row) * D + k0 + ((lc ^ (row & 7)) * 8),
                  &As[(wave * 16 + j * 8) * 64]);
        }
        const int rowB = wave * 8 + lr;
        gld16(WfT + (size_t)(col0 + rowB) * D + k0 + ((lc ^ (rowB & 7)) * 8),
              &Bs[(wave * 8) * 64]);
    };

    stage(0);
    stage(1);

    for (int i = 0; i < 16; ++i) {
        // stage i must be landed; stage i+1's 3 loads may stay in flight.
        // vmcnt waits oldest-first (m135) -> vmcnt(3) completes stage i.
        if (i < 15) asm volatile("s_waitcnt vmcnt(3)" ::: "memory");
        else        asm volatile("s_waitcnt vmcnt(0)" ::: "memory");
        __builtin_amdgcn_s_barrier();   // all waves' stage-i writes visible

        const int buf = i - (i / 3) * 3;
        bf16* As = (bf16*)(smem + buf * 24576);
        bf16* Bs = (bf16*)(smem + buf * 24576 + 16384);
        __builtin_amdgcn_s_setprio(1);
#pragma unroll
        for (int ks = 0; ks < 2; ++ks) {
            bf16x8 af[2], bfr[2];
#pragma unroll
            for (int mt = 0; mt < 2; ++mt)
                af[mt] = *(const bf16x8*)&As[(wm + mt * 16 + l15) * 64 + (((ks * 4 + quad) ^ (l15 & 7)) * 8)];
#pragma unroll
            for (int nt = 0; nt < 2; ++nt)
                bfr[nt] = *(const bf16x8*)&Bs[(wn + nt * 16 + l15) * 64 + (((ks * 4 + quad) ^ (l15 & 7)) * 8)];
#pragma unroll
            for (int mt = 0; mt < 2; ++mt)
#pragma unroll
                for (int nt = 0; nt < 2; ++nt)
                    acc[mt][nt] = __builtin_amdgcn_mfma_f32_16x16x32_bf16(af[mt], bfr[nt], acc[mt][nt], 0, 0, 0);
        }
        __builtin_amdgcn_s_setprio(0);
        // issue stage i+2 into buf (i+2)%3 == (i-1)%3: consumed in iter i-1,
        // and every wave passed THIS iter's barrier before we got here -> safe.
        if (i < 14) stage(i + 2);
    }
    __syncthreads();   // all reads done before Ofs overwrite (vmcnt already 0)

    // Epilogue: +bias -> LDS fp32 p68 -> float4 stores.
    float* Ofs = (float*)smem;   // 128 x 68 fp32 = 34816 B
    float bias[2];
#pragma unroll
    for (int nt = 0; nt < 2; ++nt) bias[nt] = bfv[col0 + wn + nt * 16 + l15];
#pragma unroll
    for (int mt = 0; mt < 2; ++mt)
#pragma unroll
        for (int reg = 0; reg < 4; ++reg) {
            const int row = wm + mt * 16 + quad * 4 + reg;
#pragma unroll
            for (int nt = 0; nt < 2; ++nt)
                Ofs[row * 68 + wn + nt * 16 + l15] = acc[mt][nt][reg] + bias[nt];
        }
    __syncthreads();
    for (int i = tid; i < 2048; i += 512) {
        const int row = i >> 4, c = (i & 15) * 4;
        *(float4*)(out + (size_t)(row0 + row) * D + col0 + c) = *(const float4*)&Ofs[row * 68 + c];
    }
}

// ---------------------------------------------------------------------------
extern "C" void kernel_launch(void* const* d_in, const int* in_sizes, int n_in,
                              void* d_out, int out_size, void* d_ws, size_t ws_size,
                              hipStream_t stream) {
    const float* X   = (const float*)d_in[0];
    const int* mask  = (const int*)d_in[1];
    const float* Wq  = (const float*)d_in[2];
    const float* bq  = (const float*)d_in[3];
    const float* Wk  = (const float*)d_in[4];
    const float* bk  = (const float*)d_in[5];   // cancels in softmax (exact)
    const float* Wv  = (const float*)d_in[6];
    const float* bv  = (const float*)d_in[7];
    const float* Wf  = (const float*)d_in[8];
    const float* bfv = (const float*)d_in[9];
    float* out = (float*)d_out;
    (void)bk;

    bf16* wsb = (bf16*)d_ws;
    const size_t QN = (size_t)B * H * T * DH;   // 4,194,304
    bf16* Ob  = wsb;
    bf16* WfT = wsb + QN;                       // 1,048,576

    qkv_attn<<<dim3(768), 256, 0, stream>>>(X, mask, Wq, Wk, Wv, bq, bv, Wf, WfT, Ob);
    fuse_mfma<<<dim3(D / 64, (B * T) / 128), 512, 0, stream>>>(Ob, WfT, bfv, out);
}

// Round 13
// 122.462 us; speedup vs baseline: 1.0143x; 1.0143x over previous
//
#include <hip/hip_runtime.h>
#include <math.h>

#define B 8
#define T 512
#define D 1024
#define H 16
#define DH 64

typedef __bf16 bf16;
typedef __attribute__((ext_vector_type(8))) __bf16 bf16x8;
typedef __attribute__((ext_vector_type(4))) __bf16 bf16x4;
typedef __attribute__((ext_vector_type(4))) float f32x4;

// Async global->LDS, 16 B per lane. LDS dest = wave-uniform base + lane*16.
__device__ __forceinline__ void gld16(const void* g, void* l) {
    __builtin_amdgcn_global_load_lds(
        (const __attribute__((address_space(1))) void*)g,
        (__attribute__((address_space(3))) void*)l, 16, 0, 0);
}

// MFMA 16x16x32 bf16 layouts (HW-verified per guide m89/m120):
//   A[m][k]: m = lane&15, k = (lane>>4)*8 + j
//   B[k][n]: n = lane&15, k = (lane>>4)*8 + j   (same lane map as A!)
//   C/D    : col = lane&15, row = (lane>>4)*4 + reg
// mfma(x,y) with both frags read at rows base+l15 yields
// D[x-row = quad*4+reg][y-row = l15].
//
// R13 (vs R11-best 121.9us; R12's 3-lever bundle regressed and is fully
// reverted). SINGLE change: fold the 256 Wf-rider blocks into the 512 attn
// blocks as a per-block HALF-TILE PROLOGUE (R5's verified phase-0 body).
// Grid 768 -> 512 = EXACTLY one full-device round at 2 blocks/CU: the 0.5
// scheduling round that serialized after the first 512 blocks disappears;
// the ~2-3us prologue hides inside each block's existing prefetch shadow.
// attn body = R11 verbatim (K-elim + T4 lgkm-barrier + T5 setprio).
// fuse = R9-verified verbatim (counted-vmcnt triple-buffer, NO setprio).

#define EXP2SCALE 1.44269504088896f   // log2(e); folded into Q pre-scale

// ---------------------------------------------------------------------------
// Kernel A (grid 512): prologue = half Wf-transpose tile; then fused
// qkv + flash attention (R11 K-elim structure).
// ---------------------------------------------------------------------------
__global__ __launch_bounds__(256, 2) void qkv_attn(
    const float* __restrict__ X, const int* __restrict__ mask,
    const float* __restrict__ Wq, const float* __restrict__ Wk,
    const float* __restrict__ Wv,
    const float* __restrict__ bq, const float* __restrict__ bv,
    const float* __restrict__ Wf, bf16* __restrict__ WfT,
    bf16* __restrict__ Ob)
{
    __shared__ __align__(16) char smem[61952];

    const int bid = blockIdx.x, tid = threadIdx.x;
    const int wave = tid >> 6, lane = tid & 63;
    const int quad = lane >> 4, l15 = lane & 15;

    const int bh = bid & 127, q0 = (bid >> 7) * 128;
    const int b = bh >> 4, h = bh & 15;

    // X key-tile prefetch addressing (wave w -> keys w*16..w*16+15)
    const int pkrow = wave * 16 + (lane >> 2);
    const int pc0 = (lane & 3) * 2;

    // ---- prefetch tile 0 (X rows + mask) into registers (overlaps the
    // prologue's Wf loads below) ----
    float4 px0, px1, px2, px3;
    {
        const float* src = X + (size_t)(b * T + pkrow) * D + h * DH + pc0 * 8;
        px0 = *(const float4*)src; px1 = *(const float4*)(src + 4);
        px2 = *(const float4*)(src + 8); px3 = *(const float4*)(src + 12);
    }
    int mreg = (tid < 64) ? mask[(size_t)b * T + tid] : 0;

    float bqr[4], bvr[4];
#pragma unroll
    for (int nt = 0; nt < 4; ++nt) {
        bqr[nt] = bq[h * DH + nt * 16 + l15];
        bvr[nt] = bv[h * DH + nt * 16 + l15];
    }

    // ================= prologue: half Wf tile (R5 phase-0, verified) ======
    {
        bf16* Ts = (bf16*)smem;   // 32 x 72
        const int tj = bid >> 1, half = bid & 1;
        const int k0 = (tj >> 4) * 64, n0 = (tj & 15) * 64 + half * 32;
        for (int i = tid; i < 512; i += 256) {
            const int k = i >> 3, nq = (i & 7) * 4;
            const float4 w = *(const float4*)(Wf + (size_t)(k0 + k) * D + n0 + nq);
            Ts[(nq + 0) * 72 + k] = (bf16)w.x; Ts[(nq + 1) * 72 + k] = (bf16)w.y;
            Ts[(nq + 2) * 72 + k] = (bf16)w.z; Ts[(nq + 3) * 72 + k] = (bf16)w.w;
        }
        __syncthreads();
        for (int i = tid; i < 256; i += 256) {
            const int n = i >> 3, kc = (i & 7) * 8;
            *(bf16x8*)(WfT + (size_t)(n0 + n) * D + k0 + kc) = *(const bf16x8*)&Ts[n * 72 + kc];
        }
        __syncthreads();   // Ts reads done; smem reusable
    }

    // LDS map (61952 B):
    //   0     : Wvs [e][d] swz, 8192, persistent
    //   8192  : Xkt dbuf, 2 x 8192 ([key64][64] swz)
    //   24576 : Vts dbuf, 2 x 9216 ([e][key] p72)
    //   43008 : Pl, 4 wave strips 32x72 (18432)
    //   61440 : msk, 2 x 64 ints
    // setup aliases (dead regions; barriers enforce):
    //   Wqs  [e][d] = Xkt buf0 (8192)
    //   WksT [d][e] = Vts buf0 (8192 <= 9216)
    //   Xq / Stage / Ostage = Pl
    bf16* Wvs  = (bf16*)(smem);
    bf16* Pl   = (bf16*)(smem + 43008);
    int*  msk  = (int*)(smem + 61440);
    bf16* Wqs  = (bf16*)(smem + 8192);
    bf16* WksT = (bf16*)(smem + 24576);
    bf16* Xq   = Pl;
    bf16* Stage = Pl;
    bf16* Ostage = Pl;

    // ---- setup: W staging. Wq/Wv -> [e][d] swz (scalar); Wk -> [d][e] swz
    // (packed bf16x4: 4 consecutive e within one chunk). ----
    for (int i = tid; i < 1024; i += 256) {
        const int d = i >> 4, eq4 = (i & 15) * 4;
        const float4 wq4 = *(const float4*)(Wq + (size_t)h * 4096 + d * 64 + eq4);
        const float4 wk4 = *(const float4*)(Wk + (size_t)h * 4096 + d * 64 + eq4);
        const float4 wv4 = *(const float4*)(Wv + (size_t)h * 4096 + d * 64 + eq4);
#pragma unroll
        for (int j = 0; j < 4; ++j) {
            const int e = eq4 + j;
            const int idx = e * 64 + (((d >> 3) ^ (e & 7)) * 8) + (d & 7);
            Wqs[idx] = (bf16)((const float*)&wq4)[j];
            Wvs[idx] = (bf16)((const float*)&wv4)[j];
        }
        bf16x4 wkp;
        wkp[0] = (bf16)wk4.x; wkp[1] = (bf16)wk4.y;
        wkp[2] = (bf16)wk4.z; wkp[3] = (bf16)wk4.w;
        *(bf16x4*)&WksT[d * 64 + (((eq4 >> 3) ^ (d & 7)) * 8) + (eq4 & 7)] = wkp;
    }
    for (int i = tid; i < 1024; i += 256) {
        const int row = i >> 3, c = i & 7;
        const float* src = X + (size_t)(b * T + q0 + row) * D + h * DH + c * 8;
        const float4 x0 = *(const float4*)src;
        const float4 x1 = *(const float4*)(src + 4);
        bf16x8 t;
        t[0] = (bf16)x0.x; t[1] = (bf16)x0.y; t[2] = (bf16)x0.z; t[3] = (bf16)x0.w;
        t[4] = (bf16)x1.x; t[5] = (bf16)x1.y; t[6] = (bf16)x1.z; t[7] = (bf16)x1.w;
        *(bf16x8*)&Xq[row * 64 + ((c ^ (row & 7)) * 8)] = t;
    }
    __syncthreads();

    // ---- Q = Xq @ WqT (+bias, x 0.125*log2e), C-layout -> Stage -> qf ----
    {
        f32x4 accQ[2][4] = {};
#pragma unroll
        for (int ks = 0; ks < 2; ++ks) {
            bf16x8 af[2], bfr[4];
#pragma unroll
            for (int mt = 0; mt < 2; ++mt) {
                const int row = wave * 32 + mt * 16 + l15;
                af[mt] = *(const bf16x8*)&Xq[row * 64 + (((ks * 4 + quad) ^ (l15 & 7)) * 8)];
            }
#pragma unroll
            for (int nt = 0; nt < 4; ++nt)
                bfr[nt] = *(const bf16x8*)&Wqs[(nt * 16 + l15) * 64 + (((ks * 4 + quad) ^ (l15 & 7)) * 8)];
#pragma unroll
            for (int mt = 0; mt < 2; ++mt)
#pragma unroll
                for (int nt = 0; nt < 4; ++nt)
                    accQ[mt][nt] = __builtin_amdgcn_mfma_f32_16x16x32_bf16(af[mt], bfr[nt], accQ[mt][nt], 0, 0, 0);
        }
        __syncthreads();   // Xq/Wqs reads done everywhere (Wqs = Xkt buf0 freed)
        const float qs = 0.125f * EXP2SCALE;
#pragma unroll
        for (int mt = 0; mt < 2; ++mt)
#pragma unroll
            for (int nt = 0; nt < 4; ++nt)
#pragma unroll
                for (int reg = 0; reg < 4; ++reg)
                    Stage[(wave * 32 + mt * 16 + quad * 4 + reg) * 72 + nt * 16 + l15] =
                        (bf16)((accQ[mt][nt][reg] + bqr[nt]) * qs);
        __builtin_amdgcn_wave_barrier();
    }
    bf16x8 qf[2][2];
#pragma unroll
    for (int mt = 0; mt < 2; ++mt)
#pragma unroll
        for (int ks = 0; ks < 2; ++ks)
            qf[mt][ks] = *(const bf16x8*)&Stage[(wave * 32 + mt * 16 + l15) * 72 + ks * 32 + quad * 8];

    // ---- Qm = Qs @ Wk (K never materialized; see R11 derivation) ----
    bf16x8 qmf[2][2];
    {
        f32x4 accM[2][4] = {};
#pragma unroll
        for (int ks = 0; ks < 2; ++ks)
#pragma unroll
            for (int nt = 0; nt < 4; ++nt) {
                const bf16x8 wk8 = *(const bf16x8*)&WksT[(nt * 16 + l15) * 64 + (((ks * 4 + quad) ^ (l15 & 7)) * 8)];
#pragma unroll
                for (int mt = 0; mt < 2; ++mt)
                    accM[mt][nt] = __builtin_amdgcn_mfma_f32_16x16x32_bf16(wk8, qf[mt][ks], accM[mt][nt], 0, 0, 0);
            }
        __builtin_amdgcn_wave_barrier();   // qf reads complete (forced by mfma deps)
#pragma unroll
        for (int mt = 0; mt < 2; ++mt)
#pragma unroll
            for (int nt = 0; nt < 4; ++nt) {
                bf16x4 qp;
#pragma unroll
                for (int reg = 0; reg < 4; ++reg) qp[reg] = (bf16)accM[mt][nt][reg];
                *(bf16x4*)&Stage[(wave * 32 + mt * 16 + l15) * 72 + nt * 16 + quad * 4] = qp;
            }
        __builtin_amdgcn_wave_barrier();
#pragma unroll
        for (int mt = 0; mt < 2; ++mt)
#pragma unroll
            for (int ks = 0; ks < 2; ++ks)
                qmf[mt][ks] = *(const bf16x8*)&Stage[(wave * 32 + mt * 16 + l15) * 72 + ks * 32 + quad * 8];
    }
    __syncthreads();   // WksT (= Vts buf0) reads done everywhere before K-loop

    f32x4 acc[2][4] = {};
    float lst2[2] = {0.f, 0.f};

    // ---- K-loop: 8 tiles of 64 keys, ONE T4 barrier per tile ----
    for (int kt = 0; kt < 8; ++kt) {
        const int p = kt & 1;
        bf16* Xkt = (bf16*)(smem + 8192 + p * 8192);
        bf16* Vts = (bf16*)(smem + 24576 + p * 9216);

        // stage prefetched X -> Xkt[p] (own rows), msk -> LDS
        {
            bf16x8 t0, t1;
            t0[0] = (bf16)px0.x; t0[1] = (bf16)px0.y; t0[2] = (bf16)px0.z; t0[3] = (bf16)px0.w;
            t0[4] = (bf16)px1.x; t0[5] = (bf16)px1.y; t0[6] = (bf16)px1.z; t0[7] = (bf16)px1.w;
            t1[0] = (bf16)px2.x; t1[1] = (bf16)px2.y; t1[2] = (bf16)px2.z; t1[3] = (bf16)px2.w;
            t1[4] = (bf16)px3.x; t1[5] = (bf16)px3.y; t1[6] = (bf16)px3.z; t1[7] = (bf16)px3.w;
            *(bf16x8*)&Xkt[pkrow * 64 + ((pc0 ^ (pkrow & 7)) * 8)] = t0;
            *(bf16x8*)&Xkt[pkrow * 64 + (((pc0 + 1) ^ (pkrow & 7)) * 8)] = t1;
            if (tid < 64) msk[p * 64 + tid] = mreg;
        }
        __builtin_amdgcn_wave_barrier();   // wave-local Xkt write->read (afkv)

        // issue prefetch for tile kt+1 (stays in flight across T4 barrier)
        if (kt < 7) {
            const float* src = X + (size_t)(b * T + (kt + 1) * 64 + pkrow) * D + h * DH + pc0 * 8;
            px0 = *(const float4*)src; px1 = *(const float4*)(src + 4);
            px2 = *(const float4*)(src + 8); px3 = *(const float4*)(src + 12);
            if (tid < 64) mreg = mask[(size_t)b * T + (kt + 1) * 64 + tid];
        }

        // V tile via MFMA (wave computes its own 16 keys); K path GONE.
        {
            bf16x8 afkv[2];
#pragma unroll
            for (int ks = 0; ks < 2; ++ks)
                afkv[ks] = *(const bf16x8*)&Xkt[(wave * 16 + l15) * 64 + (((ks * 4 + quad) ^ (l15 & 7)) * 8)];
            f32x4 accV[4] = {};
            __builtin_amdgcn_s_setprio(1);
#pragma unroll
            for (int ks = 0; ks < 2; ++ks)
#pragma unroll
                for (int nt = 0; nt < 4; ++nt) {
                    const bf16x8 bv8 = *(const bf16x8*)&Wvs[(nt * 16 + l15) * 64 + (((ks * 4 + quad) ^ (l15 & 7)) * 8)];
                    accV[nt] = __builtin_amdgcn_mfma_f32_16x16x32_bf16(afkv[ks], bv8, accV[nt], 0, 0, 0);
                }
            __builtin_amdgcn_s_setprio(0);
#pragma unroll
            for (int nt = 0; nt < 4; ++nt) {
                bf16x4 vp;
#pragma unroll
                for (int reg = 0; reg < 4; ++reg) vp[reg] = (bf16)accV[nt][reg];
                *(bf16x4*)&Vts[(nt * 16 + l15) * 72 + wave * 16 + quad * 4] = vp;
            }
        }
        // T4 barrier: LDS visibility only (Xkt all-rows + Vts + msk);
        // thread-private VMEM prefetch stays in flight.
        asm volatile("s_waitcnt lgkmcnt(0)" ::: "memory");
        __builtin_amdgcn_s_barrier();

        // S^T = Xkt Qm^T directly: s[nt] holds S[key=nt*16+quad*4+reg][q=mt*16+l15]
        bf16* Plw = Pl + wave * (32 * 72);
        {
            bf16x8 xkf[4][2];
#pragma unroll
            for (int nt = 0; nt < 4; ++nt)
#pragma unroll
                for (int ks = 0; ks < 2; ++ks)
                    xkf[nt][ks] = *(const bf16x8*)&Xkt[(nt * 16 + l15) * 64 + (((ks * 4 + quad) ^ (l15 & 7)) * 8)];
            int4 mv4[4];
#pragma unroll
            for (int nt = 0; nt < 4; ++nt)
                mv4[nt] = *(const int4*)&msk[p * 64 + nt * 16 + quad * 4];
#pragma unroll
            for (int mt = 0; mt < 2; ++mt) {
                f32x4 s[4] = {};
                __builtin_amdgcn_s_setprio(1);
#pragma unroll
                for (int ks = 0; ks < 2; ++ks)
#pragma unroll
                    for (int nt = 0; nt < 4; ++nt)
                        s[nt] = __builtin_amdgcn_mfma_f32_16x16x32_bf16(xkf[nt][ks], qmf[mt][ks], s[nt], 0, 0, 0);
                __builtin_amdgcn_s_setprio(0);
#pragma unroll
                for (int nt = 0; nt < 4; ++nt) {
                    bf16x4 pp;
                    const float p0 = (mv4[nt].x > 0) ? exp2f(s[nt][0]) : 0.f;
                    const float p1 = (mv4[nt].y > 0) ? exp2f(s[nt][1]) : 0.f;
                    const float p2 = (mv4[nt].z > 0) ? exp2f(s[nt][2]) : 0.f;
                    const float p3 = (mv4[nt].w > 0) ? exp2f(s[nt][3]) : 0.f;
                    lst2[mt] += (p0 + p1) + (p2 + p3);
                    pp[0] = (bf16)p0; pp[1] = (bf16)p1; pp[2] = (bf16)p2; pp[3] = (bf16)p3;
                    *(bf16x4*)&Plw[(mt * 16 + l15) * 72 + nt * 16 + quad * 4] = pp;
                }
            }
        }
        __builtin_amdgcn_wave_barrier();   // wave-local P write->read

        // O += P V
        __builtin_amdgcn_s_setprio(1);
#pragma unroll
        for (int kc = 0; kc < 2; ++kc) {
            const bf16x8 pf0 = *(const bf16x8*)&Plw[(l15) * 72 + kc * 32 + quad * 8];
            const bf16x8 pf1 = *(const bf16x8*)&Plw[(16 + l15) * 72 + kc * 32 + quad * 8];
#pragma unroll
            for (int nt = 0; nt < 4; ++nt) {
                const bf16x8 vf = *(const bf16x8*)&Vts[(nt * 16 + l15) * 72 + kc * 32 + quad * 8];
                acc[0][nt] = __builtin_amdgcn_mfma_f32_16x16x32_bf16(pf0, vf, acc[0][nt], 0, 0, 0);
                acc[1][nt] = __builtin_amdgcn_mfma_f32_16x16x32_bf16(pf1, vf, acc[1][nt], 0, 0, 0);
            }
        }
        __builtin_amdgcn_s_setprio(0);
    }

    // ---- epilogue: reduce l across quads, redistribute, +bv, store ----
    __builtin_amdgcn_wave_barrier();
    float inv_r[2][4];
#pragma unroll
    for (int mt = 0; mt < 2; ++mt) {
        float l = lst2[mt];
        l += __shfl_xor(l, 16);
        l += __shfl_xor(l, 32);
        const float inv = 1.f / l;
#pragma unroll
        for (int reg = 0; reg < 4; ++reg)
            inv_r[mt][reg] = __shfl(inv, (lane & 48) | (quad * 4 + reg));
    }
#pragma unroll
    for (int mt = 0; mt < 2; ++mt)
#pragma unroll
        for (int reg = 0; reg < 4; ++reg) {
            const int row = wave * 32 + mt * 16 + quad * 4 + reg;   // own strip
#pragma unroll
            for (int nt = 0; nt < 4; ++nt)
                Ostage[row * 72 + nt * 16 + l15] =
                    (bf16)(acc[mt][nt][reg] * inv_r[mt][reg] + bvr[nt]);
        }
    __syncthreads();
    for (int i = tid; i < 1024; i += 256) {
        const int row = i >> 3, c = (i & 7) * 8;
        *(bf16x8*)(Ob + ((size_t)b * T + q0 + row) * D + h * DH + c) =
            *(const bf16x8*)&Ostage[row * 72 + c];
    }
}

// ---------------------------------------------------------------------------
// Kernel B: fusion GEMM, 128M x 64N, 512 thr (8 waves), grid (16,32)=512
// -> 2 blocks/CU = 4 waves/SIMD. TRIPLE-buffered, counted vmcnt pipeline
// (R9-verified verbatim; R12's setprio reverted).
// ---------------------------------------------------------------------------
__global__ __launch_bounds__(512, 4) void fuse_mfma(
    const bf16* __restrict__ Ob, const bf16* __restrict__ WfT,
    const float* __restrict__ bfv, float* __restrict__ out)
{
    __shared__ __align__(16) char smem[73728];
    // buf t%3 at t*24576: As 128x64 (16384 B) + Bs 64x64 (8192 B).

    const int col0 = blockIdx.x * 64;
    const int row0 = blockIdx.y * 128;
    const int tid = threadIdx.x, wave = tid >> 6, lane = tid & 63;
    const int quad = lane >> 4, l15 = lane & 15;
    const int lr = lane >> 3, lc = lane & 7;
    const int wm = (wave >> 1) * 32, wn = (wave & 1) * 32;

    f32x4 acc[2][2] = {};

    // per wave: 3 gld16 per stage (2 A-rows-of-8 + 1 B-rows-of-8)
    auto stage = [&](int t) {
        const int buf = t - (t / 3) * 3;
        bf16* As = (bf16*)(smem + buf * 24576);
        bf16* Bs = (bf16*)(smem + buf * 24576 + 16384);
        const int k0 = t * 64;
#pragma unroll
        for (int j = 0; j < 2; ++j) {
            const int row = wave * 16 + j * 8 + lr;
            gld16(Ob + (size_t)(row0 + row) * D + k0 + ((lc ^ (row & 7)) * 8),
                  &As[(wave * 16 + j * 8) * 64]);
        }
        const int rowB = wave * 8 + lr;
        gld16(WfT + (size_t)(col0 + rowB) * D + k0 + ((lc ^ (rowB & 7)) * 8),
              &Bs[(wave * 8) * 64]);
    };

    stage(0);
    stage(1);

    for (int i = 0; i < 16; ++i) {
        // stage i must be landed; stage i+1's 3 loads may stay in flight.
        // vmcnt waits oldest-first (m135) -> vmcnt(3) completes stage i.
        if (i < 15) asm volatile("s_waitcnt vmcnt(3)" ::: "memory");
        else        asm volatile("s_waitcnt vmcnt(0)" ::: "memory");
        __builtin_amdgcn_s_barrier();   // all waves' stage-i writes visible

        const int buf = i - (i / 3) * 3;
        bf16* As = (bf16*)(smem + buf * 24576);
        bf16* Bs = (bf16*)(smem + buf * 24576 + 16384);
#pragma unroll
        for (int ks = 0; ks < 2; ++ks) {
            bf16x8 af[2], bfr[2];
#pragma unroll
            for (int mt = 0; mt < 2; ++mt)
                af[mt] = *(const bf16x8*)&As[(wm + mt * 16 + l15) * 64 + (((ks * 4 + quad) ^ (l15 & 7)) * 8)];
#pragma unroll
            for (int nt = 0; nt < 2; ++nt)
                bfr[nt] = *(const bf16x8*)&Bs[(wn + nt * 16 + l15) * 64 + (((ks * 4 + quad) ^ (l15 & 7)) * 8)];
#pragma unroll
            for (int mt = 0; mt < 2; ++mt)
#pragma unroll
                for (int nt = 0; nt < 2; ++nt)
                    acc[mt][nt] = __builtin_amdgcn_mfma_f32_16x16x32_bf16(af[mt], bfr[nt], acc[mt][nt], 0, 0, 0);
        }
        // issue stage i+2 into buf (i+2)%3 == (i-1)%3: consumed in iter i-1,
        // and every wave passed THIS iter's barrier before we got here -> safe.
        if (i < 14) stage(i + 2);
    }
    __syncthreads();   // all reads done before Ofs overwrite (vmcnt already 0)

    // Epilogue: +bias -> LDS fp32 p68 -> float4 stores.
    float* Ofs = (float*)smem;   // 128 x 68 fp32 = 34816 B
    float bias[2];
#pragma unroll
    for (int nt = 0; nt < 2; ++nt) bias[nt] = bfv[col0 + wn + nt * 16 + l15];
#pragma unroll
    for (int mt = 0; mt < 2; ++mt)
#pragma unroll
        for (int reg = 0; reg < 4; ++reg) {
            const int row = wm + mt * 16 + quad * 4 + reg;
#pragma unroll
            for (int nt = 0; nt < 2; ++nt)
                Ofs[row * 68 + wn + nt * 16 + l15] = acc[mt][nt][reg] + bias[nt];
        }
    __syncthreads();
    for (int i = tid; i < 2048; i += 512) {
        const int row = i >> 4, c = (i & 15) * 4;
        *(float4*)(out + (size_t)(row0 + row) * D + col0 + c) = *(const float4*)&Ofs[row * 68 + c];
    }
}

// ---------------------------------------------------------------------------
extern "C" void kernel_launch(void* const* d_in, const int* in_sizes, int n_in,
                              void* d_out, int out_size, void* d_ws, size_t ws_size,
                              hipStream_t stream) {
    const float* X   = (const float*)d_in[0];
    const int* mask  = (const int*)d_in[1];
    const float* Wq  = (const float*)d_in[2];
    const float* bq  = (const float*)d_in[3];
    const float* Wk  = (const float*)d_in[4];
    const float* bk  = (const float*)d_in[5];   // cancels in softmax (exact)
    const float* Wv  = (const float*)d_in[6];
    const float* bv  = (const float*)d_in[7];
    const float* Wf  = (const float*)d_in[8];
    const float* bfv = (const float*)d_in[9];
    float* out = (float*)d_out;
    (void)bk;

    bf16* wsb = (bf16*)d_ws;
    const size_t QN = (size_t)B * H * T * DH;   // 4,194,304
    bf16* Ob  = wsb;
    bf16* WfT = wsb + QN;                       // 1,048,576

    qkv_attn<<<dim3(512), 256, 0, stream>>>(X, mask, Wq, Wk, Wv, bq, bv, Wf, WfT, Ob);
    fuse_mfma<<<dim3(D / 64, (B * T) / 128), 512, 0, stream>>>(Ob, WfT, bfv, out);
}